// Round 8
// baseline (404.994 us; speedup 1.0000x reference)
//
#include <hip/hip_runtime.h>
#include <hip/hip_bf16.h>

#define NHEAD 4
#define FIN   768
#define FOUT  64
#define BSZ   4
#define NSEQ  2048
#define BH    (BSZ*NHEAD)
#define LOG2E 1.44269504088896f

typedef __attribute__((ext_vector_type(8)))  short bf16x8;   // MFMA A/B frag
typedef __attribute__((ext_vector_type(16))) float f32x16;   // MFMA 32x32 C/D
typedef __attribute__((ext_vector_type(4)))  unsigned u32x4;

__device__ __forceinline__ float fexp2(float x){
#if __has_builtin(__builtin_amdgcn_exp2f)
  return __builtin_amdgcn_exp2f(x);
#else
  return exp2f(x);
#endif
}
__device__ __forceinline__ unsigned short f2bf(float f){
  unsigned b = __float_as_uint(f);
  return (unsigned short)((b + 0x7fffu + ((b >> 16) & 1u)) >> 16);
}
__device__ __forceinline__ unsigned pkbf(float lo, float hi){
#if __has_builtin(__builtin_amdgcn_cvt_pk_bf16_f32)
  typedef __attribute__((ext_vector_type(2))) __bf16 bf2;
  union { bf2 v; unsigned u; } cv;
  cv.v = __builtin_amdgcn_cvt_pk_bf16_f32(lo, hi);
  return cv.u;
#else
  return (unsigned)f2bf(lo) | ((unsigned)f2bf(hi) << 16);
#endif
}
// fast tanh via exp2: tanh(v) = 1 - 2/(exp2(2*log2e*v)+1). |err| ~1e-7.
__device__ __forceinline__ float fast_tanh(float v){
  const float e = fexp2(v * (2.0f*LOG2E));
#if __has_builtin(__builtin_amdgcn_rcpf)
  return 1.0f - 2.0f*__builtin_amdgcn_rcpf(e + 1.0f);
#else
  return 1.0f - 2.0f/(e + 1.0f);
#endif
}

// ---------------------------------------------------------------------------
// Kernel A v6: same proven MFMA GEMM + pipelined staging as v5, but the
// epilogue now writes h' as plain FP32 row-major [bh][j][64] (no bf16 pack,
// no Tt transpose staging, no hpz2 chunk layout). srcv/dstv unchanged
// (log2e-scaled). XCD swizzle unchanged.
// ---------------------------------------------------------------------------
__global__ __launch_bounds__(512, 4) void k_hprime(
    const float* __restrict__ h, const float* __restrict__ w,
    const float* __restrict__ a_src, const float* __restrict__ a_dst,
    float* __restrict__ hp32, float* __restrict__ srcv,
    float* __restrict__ dstv)
{
  __shared__ __align__(16) char smem[65536];
  // A0@0, A1@16384, B0@32768, B1@49152
  // epilogue overlays: scratch@0 (16K), psumS@16384, psumD@16896
  float* psumS = (float*)(smem + 16384);
  float* psumD = (float*)(smem + 16896);

  const int tid  = threadIdx.x;
  const int bid  = blockIdx.x;
  const int bh1  = (bid & 7) | (((bid >> 3) & 1) << 3);
  const int head = bh1 & 3;
  const int jbase = (bid >> 4) << 6;                 // within-sequence row base
  const int i0a   = (bh1 >> 2)*NSEQ + jbase;         // global flat row
  const int wave = tid >> 6, lane = tid & 63;
  const int wm = wave & 1, wn = (wave >> 1) & 1, kw = wave >> 2;
  const int l32 = lane & 31, h32 = lane >> 5;

  f32x16 acc = {0,0,0,0,0,0,0,0,0,0,0,0,0,0,0,0};

  // A staging map: row sr, chunk sc (r9-proven)
  const int sr = tid >> 3, sc = tid & 7;
  const float* hA = h + (size_t)(i0a + sr)*FIN + sc*8;
  const int aslot = (sc ^ (sr & 7)) << 4;

  // B staging map: o = lane (coalesced), halves g0 = cc, g1 = cc+8
  const int ob = tid & 63, cc = tid >> 6;
  const float* wsrc = w + (size_t)head*FIN*FOUT + ob;   // + f*64
  const int bslot0 = ((cc & 7) ^ (ob & 7)) << 4;        // half 0 slot

  // prologue: prefetch iter 0
  float4 ra0 = *(const float4*)(hA);
  float4 ra1 = *(const float4*)(hA + 4);
  float4 ra2 = *(const float4*)(hA + 64);
  float4 ra3 = *(const float4*)(hA + 68);
  float rb[16];
  #pragma unroll
  for (int j = 0; j < 8; ++j){
    rb[j]     = wsrc[(size_t)(cc*8 + j)*FOUT];          // g0 = cc   (k 0..63)
    rb[8 + j] = wsrc[(size_t)(64 + cc*8 + j)*FOUT];     // g1 = cc+8 (k 64..127)
  }

  for (int it = 0; it < 6; ++it){
    char* Ab = smem +         (it & 1)*16384;
    char* Bb = smem + 32768 + (it & 1)*16384;
    u32x4 pk0, pk1;
    pk0[0] = pkbf(ra0.x, ra0.y); pk0[1] = pkbf(ra0.z, ra0.w);
    pk0[2] = pkbf(ra1.x, ra1.y); pk0[3] = pkbf(ra1.z, ra1.w);
    pk1[0] = pkbf(ra2.x, ra2.y); pk1[1] = pkbf(ra2.z, ra2.w);
    pk1[2] = pkbf(ra3.x, ra3.y); pk1[3] = pkbf(ra3.z, ra3.w);
    u32x4 qb0, qb1;
    qb0[0] = pkbf(rb[0],  rb[1]);  qb0[1] = pkbf(rb[2],  rb[3]);
    qb0[2] = pkbf(rb[4],  rb[5]);  qb0[3] = pkbf(rb[6],  rb[7]);
    qb1[0] = pkbf(rb[8],  rb[9]);  qb1[1] = pkbf(rb[10], rb[11]);
    qb1[2] = pkbf(rb[12], rb[13]); qb1[3] = pkbf(rb[14], rb[15]);
    if (it < 5){
      const float* an = hA + (it+1)*128;
      ra0 = *(const float4*)(an);      ra1 = *(const float4*)(an + 4);
      ra2 = *(const float4*)(an + 64); ra3 = *(const float4*)(an + 68);
      const float* wn_ = wsrc + (size_t)(it+1)*128*FOUT;
      #pragma unroll
      for (int j = 0; j < 8; ++j){
        rb[j]     = wn_[(size_t)(cc*8 + j)*FOUT];
        rb[8 + j] = wn_[(size_t)(64 + cc*8 + j)*FOUT];
      }
    }
    *(u32x4*)(Ab + sr*256 + aslot)        = pk0;
    *(u32x4*)(Ab + sr*256 + 128 + aslot)  = pk1;
    *(u32x4*)(Bb + ob*256 +       bslot0) = qb0;
    *(u32x4*)(Bb + ob*256 + 128 + bslot0) = qb1;
    // LDS-only drain + raw barrier: global prefetch stays outstanding
    asm volatile("s_waitcnt lgkmcnt(0)" ::: "memory");
    __builtin_amdgcn_s_barrier();
    __builtin_amdgcn_sched_barrier(0);
    #pragma unroll
    for (int s = 0; s < 4; ++s){
      const int slot = (((s*2 + h32) ^ (l32 & 7)) << 4);
      bf16x8 av = *(const bf16x8*)(Ab + (wm*32 + l32)*256 + kw*128 + slot);
      bf16x8 bv = *(const bf16x8*)(Bb + (wn*32 + l32)*256 + kw*128 + slot);
      acc = __builtin_amdgcn_mfma_f32_32x32x16_bf16(av, bv, acc, 0, 0, 0);
    }
  }

  // kw-merge via scratch@0 (iter-5 MFMA read A1/B1 - disjoint)
  if (kw == 1) *(f32x16*)(smem + (size_t)((wave & 3)*64 + lane)*64) = acc;
  __syncthreads();
  if (kw == 0){
    acc += *(const f32x16*)(smem + (size_t)((wave & 3)*64 + lane)*64);
    const float as = a_src[head*64 + wn*32 + l32];
    const float ad = a_dst[head*64 + wn*32 + l32];
    const int orow = wn*32 + l32;
    float* hrow = hp32 + ((size_t)bh1*NSEQ + jbase)*64 + orow;
    #pragma unroll
    for (int rb2 = 0; rb2 < 4; ++rb2){
      const int jb = wm*32 + rb2*8 + h32*4;
      #pragma unroll
      for (int q = 0; q < 4; ++q){
        const float v = acc[rb2*4 + q];
        hrow[(size_t)(jb + q)*64] = v;      // fp32 h' row-major, coalesced 128B
        const float t = fast_tanh(v);
        float ps = t*as, pd = t*ad;
        ps += __shfl_xor(ps, 1);  ps += __shfl_xor(ps, 2);  ps += __shfl_xor(ps, 4);
        ps += __shfl_xor(ps, 8);  ps += __shfl_xor(ps, 16);
        pd += __shfl_xor(pd, 1);  pd += __shfl_xor(pd, 2);  pd += __shfl_xor(pd, 4);
        pd += __shfl_xor(pd, 8);  pd += __shfl_xor(pd, 16);
        if (l32 == 0){
          psumS[(jb + q)*2 + wn] = ps;
          psumD[(jb + q)*2 + wn] = pd;
        }
      }
    }
  }
  __syncthreads();
  if (tid < 64){
    // log2-domain pre-scale (|S|,|D| <= ~28.1 -> all exp2 fp32-safe)
    srcv[(size_t)bh1*NSEQ + jbase + tid] = (psumS[tid*2] + psumS[tid*2 + 1]) * LOG2E;
    dstv[(size_t)bh1*NSEQ + jbase + tid] = (psumD[tid*2] + psumD[tid*2 + 1]) * LOG2E;
  }
}

// ---------------------------------------------------------------------------
// Kernel B v5 — O(N) softmax via sorted split-point + weighted prefix/suffix
// scans. p_ij = [S_i+D_j>=0] 2^Si 2^Dj + [S_i+D_j<0] 2^{.2Si} 2^{.2Dj}.
// Per bh: bitonic-sort D (2048, LDS, with index payload); precompute
// Fh=2^D, Fl=2^{.2D}; two-level scans produce, in sorted order k:
//   P[k][c] = sum_{m<k}  Fl[m]*x_c(m)   (exclusive prefix, 0.2-branch)
//   S[k][c] = sum_{m>=k} Fh[m]*x_c(m)   (inclusive suffix, 1.0-branch,
//                                        scanned backward - no cancellation)
// where x_c = h'[perm[m]][c] for c<64, 1 for c=64 (denominator channel).
// Row i: r = lower_bound(sorted D, -S_i);
//   out[i][o] = (2^Si S[r][o] + 2^{.2Si} P[r][o])
//             / (2^Si S[r][64] + 2^{.2Si} P[r][64]) + bias[o].
// Exponent bounds |S|,|D|<=28 keep all fp32 intermediates <= 2^70.
// One block per bh (grid 16).
// ---------------------------------------------------------------------------
__global__ __launch_bounds__(512, 1) void k_attn2(
    const float* __restrict__ hp32, const float* __restrict__ srcv,
    const float* __restrict__ dstv, const float* __restrict__ bias,
    float* __restrict__ out, float* __restrict__ Pws, float* __restrict__ Sws)
{
  __shared__ float keys[2048];     // sorted D (log2e-scaled)
  __shared__ int   idxs[2048];     // permutation
  __shared__ float Fh[2048];       // 2^D
  __shared__ float Fl[2048];       // 2^{0.2 D}
  __shared__ float seg[130][32];   // per-(scan lane u, segment s) sums/bases

  const int bh  = blockIdx.x;
  const int tid = threadIdx.x;
  const float* dv = dstv + (size_t)bh*NSEQ;

  for (int k = tid; k < 2048; k += 512){ keys[k] = dv[k]; idxs[k] = k; }
  __syncthreads();

  // bitonic sort ascending (2048 = 2^11)
  for (int sz = 2; sz <= 2048; sz <<= 1){
    for (int st = sz >> 1; st > 0; st >>= 1){
      for (int t = tid; t < 2048; t += 512){
        const int j = t ^ st;
        if (j > t){
          const float a = keys[t], b = keys[j];
          const bool up = ((t & sz) == 0);
          if (up ? (a > b) : (a < b)){
            keys[t] = b; keys[j] = a;
            const int ia = idxs[t]; idxs[t] = idxs[j]; idxs[j] = ia;
          }
        }
      }
      __syncthreads();
    }
  }
  for (int k = tid; k < 2048; k += 512){
    const float d = keys[k];
    Fh[k] = fexp2(d);
    Fl[k] = fexp2(0.2f*d);
  }
  __syncthreads();

  const float* hp = hp32 + (size_t)bh*NSEQ*64;

  // pass 1: segment sums (32 segments of 64; 130 scan lanes: u<65 fwd 0.2-
  // branch channels 0..64, u>=65 backward 1.0-branch channels 0..64)
  for (int t = tid; t < 4160; t += 512){
    const int s = t / 130, u = t - s*130;
    const bool back = (u >= 65);
    const int c = back ? (u - 65) : u;
    float acc = 0.f;
    for (int q = 0; q < 64; ++q){
      const int k = s*64 + q;
      const float x = (c < 64) ? hp[(size_t)idxs[k]*64 + c] : 1.f;
      acc += (back ? Fh[k] : Fl[k]) * x;
    }
    seg[u][s] = acc;
  }
  __syncthreads();

  // pass 2: in-place exclusive prefix (fwd rows) / exclusive suffix (back rows)
  if (tid < 130){
    float run = 0.f;
    if (tid < 65){
      for (int s = 0; s < 32; ++s){ const float v = seg[tid][s]; seg[tid][s] = run; run += v; }
    } else {
      for (int s = 31; s >= 0; --s){ const float v = seg[tid][s]; seg[tid][s] = run; run += v; }
    }
  }
  __syncthreads();

  // pass 3: materialize P (exclusive prefix) and S (inclusive suffix),
  // k-major rows of 66 floats (channels 0..64 + pad) -> coalesced writes.
  float* Pb = Pws + (size_t)bh*2049*66;
  float* Sb = Sws + (size_t)bh*2049*66;
  for (int t = tid; t < 4160; t += 512){
    const int s = t / 130, u = t - s*130;
    const bool back = (u >= 65);
    const int c = back ? (u - 65) : u;
    float run = seg[u][s];
    if (!back){
      for (int q = 0; q < 64; ++q){
        const int k = s*64 + q;
        Pb[(size_t)k*66 + c] = run;
        const float x = (c < 64) ? hp[(size_t)idxs[k]*64 + c] : 1.f;
        run += Fl[k]*x;
      }
      if (s == 31) Pb[(size_t)2048*66 + c] = run;   // P[2048] = total (r=2048)
    } else {
      for (int q = 63; q >= 0; --q){
        const int k = s*64 + q;
        const float x = (c < 64) ? hp[(size_t)idxs[k]*64 + c] : 1.f;
        run += Fh[k]*x;
        Sb[(size_t)k*66 + c] = run;
      }
      if (s == 31) Sb[(size_t)2048*66 + c] = 0.f;   // S[2048] = empty suffix
    }
  }
  __threadfence();
  __syncthreads();

  // output: 16 threads per row i; binary search split point; combine.
  const int ig = tid >> 4;            // 0..31
  const int o4 = (tid & 15)*4;
  const float4 bia = *(const float4*)(bias + o4);
  const float* sv = srcv + (size_t)bh*NSEQ;
  for (int base = 0; base < 2048; base += 32){
    const int i = base + ig;
    const float S = sv[i];
    const float thr = -S;
    int lo = 0, hi = 2048;
    while (lo < hi){
      const int mid = (lo + hi) >> 1;
      if (keys[mid] < thr) lo = mid + 1; else hi = mid;
    }
    const float Ei  = fexp2(S);
    const float Eip = fexp2(0.2f*S);
    const float* Pr = Pb + (size_t)lo*66;
    const float* Sr = Sb + (size_t)lo*66;
    const float4 pn = *(const float4*)(Pr + o4);
    const float4 sn = *(const float4*)(Sr + o4);
    const float den = Ei*Sr[64] + Eip*Pr[64];
    const float rd = 1.f/den;
    float4 res;
    res.x = (Ei*sn.x + Eip*pn.x)*rd + bia.x;
    res.y = (Ei*sn.y + Eip*pn.y)*rd + bia.y;
    res.z = (Ei*sn.z + Eip*pn.z)*rd + bia.z;
    res.w = (Ei*sn.w + Eip*pn.w)*rd + bia.w;
    *(float4*)(out + ((size_t)bh*NSEQ + i)*64 + o4) = res;
  }
}

// ---------------------------------------------------------------------------
extern "C" void kernel_launch(void* const* d_in, const int* in_sizes, int n_in,
                              void* d_out, int out_size, void* d_ws, size_t ws_size,
                              hipStream_t stream)
{
  const float* h     = (const float*)d_in[0];
  const float* w     = (const float*)d_in[1];
  const float* a_src = (const float*)d_in[2];
  const float* a_dst = (const float*)d_in[3];
  const float* bias  = (const float*)d_in[4];
  float* out = (float*)d_out;

  char* ws = (char*)d_ws;
  float* hp32 = (float*)ws;                                   // 8 MB fp32 h'
  float* srcv = (float*)(ws + (8u<<20));                      // 128 KB (log2-scaled)
  float* dstv = (float*)(ws + (8u<<20) + (128u<<10));         // 128 KB (log2-scaled)
  float* Pws  = (float*)(ws + (16u<<20));                     // 8.66 MB prefix
  float* Sws  = (float*)(ws + (28u<<20));                     // 8.66 MB suffix

  k_hprime<<<512, 512, 0, stream>>>(h, w, a_src, a_dst, hp32, srcv, dstv);
  k_attn2<<<16, 512, 0, stream>>>(hp32, srcv, dstv, bias, out, Pws, Sws);
}

// Round 9
// 134.441 us; speedup vs baseline: 3.0124x; 3.0124x over previous
//
#include <hip/hip_runtime.h>
#include <hip/hip_bf16.h>

#define NHEAD 4
#define FIN   768
#define FOUT  64
#define BSZ   4
#define NSEQ  2048
#define BH    (BSZ*NHEAD)
#define LOG2E 1.44269504088896f

typedef __attribute__((ext_vector_type(8)))  short bf16x8;   // MFMA A/B frag
typedef __attribute__((ext_vector_type(16))) float f32x16;   // MFMA 32x32 C/D
typedef __attribute__((ext_vector_type(8)))  unsigned short u16x8;
typedef __attribute__((ext_vector_type(4)))  unsigned short u16x4;
typedef __attribute__((ext_vector_type(4)))  unsigned u32x4;

__device__ __forceinline__ unsigned short f2bf(float f){
  unsigned b = __float_as_uint(f);
  return (unsigned short)((b + 0x7fffu + ((b >> 16) & 1u)) >> 16);
}
__device__ __forceinline__ float fexp2(float x){
#if __has_builtin(__builtin_amdgcn_exp2f)
  return __builtin_amdgcn_exp2f(x);
#else
  return exp2f(x);
#endif
}
__device__ __forceinline__ unsigned pkbf(float lo, float hi){
#if __has_builtin(__builtin_amdgcn_cvt_pk_bf16_f32)
  typedef __attribute__((ext_vector_type(2))) __bf16 bf2;
  union { bf2 v; unsigned u; } cv;
  cv.v = __builtin_amdgcn_cvt_pk_bf16_f32(lo, hi);
  return cv.u;
#else
  return (unsigned)f2bf(lo) | ((unsigned)f2bf(hi) << 16);
#endif
}
// fast tanh via exp2: tanh(v) = 1 - 2/(exp2(2*log2e*v)+1). |err| ~1e-7.
__device__ __forceinline__ float fast_tanh(float v){
  const float e = fexp2(v * (2.0f*LOG2E));
#if __has_builtin(__builtin_amdgcn_rcpf)
  return 1.0f - 2.0f*__builtin_amdgcn_rcpf(e + 1.0f);
#else
  return 1.0f - 2.0f/(e + 1.0f);
#endif
}

// ---------------------------------------------------------------------------
// Kernel A v5 (proven, round 5): pipelined staging, lgkmcnt-only barrier
// drain, fast_tanh, (512,4). Writes bf16 chunk-linear hpz2 + srcv/dstv.
// ---------------------------------------------------------------------------
__global__ __launch_bounds__(512, 4) void k_hprime(
    const float* __restrict__ h, const float* __restrict__ w,
    const float* __restrict__ a_src, const float* __restrict__ a_dst,
    unsigned short* __restrict__ hpz2, float* __restrict__ srcv,
    float* __restrict__ dstv)
{
  __shared__ __align__(16) char smem[65536];
  float* psumS = (float*)(smem + 16384);
  float* psumD = (float*)(smem + 16896);
  char*  Tt    = smem + 32768;

  const int tid  = threadIdx.x;
  const int bid  = blockIdx.x;
  const int bh1  = (bid & 7) | (((bid >> 3) & 1) << 3);
  const int head = bh1 & 3;
  const int jbase = (bid >> 4) << 6;
  const int i0a   = (bh1 >> 2)*NSEQ + jbase;
  const int wave = tid >> 6, lane = tid & 63;
  const int wm = wave & 1, wn = (wave >> 1) & 1, kw = wave >> 2;
  const int l32 = lane & 31, h32 = lane >> 5;

  f32x16 acc = {0,0,0,0,0,0,0,0,0,0,0,0,0,0,0,0};

  const int sr = tid >> 3, sc = tid & 7;
  const float* hA = h + (size_t)(i0a + sr)*FIN + sc*8;
  const int aslot = (sc ^ (sr & 7)) << 4;

  const int ob = tid & 63, cc = tid >> 6;
  const float* wsrc = w + (size_t)head*FIN*FOUT + ob;
  const int bslot0 = ((cc & 7) ^ (ob & 7)) << 4;

  float4 ra0 = *(const float4*)(hA);
  float4 ra1 = *(const float4*)(hA + 4);
  float4 ra2 = *(const float4*)(hA + 64);
  float4 ra3 = *(const float4*)(hA + 68);
  float rb[16];
  #pragma unroll
  for (int j = 0; j < 8; ++j){
    rb[j]     = wsrc[(size_t)(cc*8 + j)*FOUT];
    rb[8 + j] = wsrc[(size_t)(64 + cc*8 + j)*FOUT];
  }

  for (int it = 0; it < 6; ++it){
    char* Ab = smem +         (it & 1)*16384;
    char* Bb = smem + 32768 + (it & 1)*16384;
    u32x4 pk0, pk1;
    pk0[0] = pkbf(ra0.x, ra0.y); pk0[1] = pkbf(ra0.z, ra0.w);
    pk0[2] = pkbf(ra1.x, ra1.y); pk0[3] = pkbf(ra1.z, ra1.w);
    pk1[0] = pkbf(ra2.x, ra2.y); pk1[1] = pkbf(ra2.z, ra2.w);
    pk1[2] = pkbf(ra3.x, ra3.y); pk1[3] = pkbf(ra3.z, ra3.w);
    u32x4 qb0, qb1;
    qb0[0] = pkbf(rb[0],  rb[1]);  qb0[1] = pkbf(rb[2],  rb[3]);
    qb0[2] = pkbf(rb[4],  rb[5]);  qb0[3] = pkbf(rb[6],  rb[7]);
    qb1[0] = pkbf(rb[8],  rb[9]);  qb1[1] = pkbf(rb[10], rb[11]);
    qb1[2] = pkbf(rb[12], rb[13]); qb1[3] = pkbf(rb[14], rb[15]);
    if (it < 5){
      const float* an = hA + (it+1)*128;
      ra0 = *(const float4*)(an);      ra1 = *(const float4*)(an + 4);
      ra2 = *(const float4*)(an + 64); ra3 = *(const float4*)(an + 68);
      const float* wn_ = wsrc + (size_t)(it+1)*128*FOUT;
      #pragma unroll
      for (int j = 0; j < 8; ++j){
        rb[j]     = wn_[(size_t)(cc*8 + j)*FOUT];
        rb[8 + j] = wn_[(size_t)(64 + cc*8 + j)*FOUT];
      }
    }
    *(u32x4*)(Ab + sr*256 + aslot)        = pk0;
    *(u32x4*)(Ab + sr*256 + 128 + aslot)  = pk1;
    *(u32x4*)(Bb + ob*256 +       bslot0) = qb0;
    *(u32x4*)(Bb + ob*256 + 128 + bslot0) = qb1;
    asm volatile("s_waitcnt lgkmcnt(0)" ::: "memory");
    __builtin_amdgcn_s_barrier();
    __builtin_amdgcn_sched_barrier(0);
    #pragma unroll
    for (int s = 0; s < 4; ++s){
      const int slot = (((s*2 + h32) ^ (l32 & 7)) << 4);
      bf16x8 av = *(const bf16x8*)(Ab + (wm*32 + l32)*256 + kw*128 + slot);
      bf16x8 bv = *(const bf16x8*)(Bb + (wn*32 + l32)*256 + kw*128 + slot);
      acc = __builtin_amdgcn_mfma_f32_32x32x16_bf16(av, bv, acc, 0, 0, 0);
    }
  }

  if (kw == 1) *(f32x16*)(smem + (size_t)((wave & 3)*64 + lane)*64) = acc;
  __syncthreads();
  if (kw == 0){
    acc += *(const f32x16*)(smem + (size_t)((wave & 3)*64 + lane)*64);
    const float as = a_src[head*64 + wn*32 + l32];
    const float ad = a_dst[head*64 + wn*32 + l32];
    #pragma unroll
    for (int rb2 = 0; rb2 < 4; ++rb2){
      const int jb = wm*32 + rb2*8 + h32*4;
      u16x4 c4;
      #pragma unroll
      for (int q = 0; q < 4; ++q){
        const float v = acc[rb2*4 + q];
        c4[q] = f2bf(v);
        const float t = fast_tanh(v);
        float ps = t*as, pd = t*ad;
        ps += __shfl_xor(ps, 1);  ps += __shfl_xor(ps, 2);  ps += __shfl_xor(ps, 4);
        ps += __shfl_xor(ps, 8);  ps += __shfl_xor(ps, 16);
        pd += __shfl_xor(pd, 1);  pd += __shfl_xor(pd, 2);  pd += __shfl_xor(pd, 4);
        pd += __shfl_xor(pd, 8);  pd += __shfl_xor(pd, 16);
        if (l32 == 0){
          psumS[(jb + q)*2 + wn] = ps;
          psumD[(jb + q)*2 + wn] = pd;
        }
      }
      const int orow = wn*32 + l32;
      const int slot = ((jb >> 3) & 7) ^ (orow & 7);
      *(u16x4*)(Tt + orow*128 + slot*16 + (jb & 7)*2) = c4;
    }
  }
  __syncthreads();

  {
    const int o = tid & 63, c = tid >> 6;
    u16x8 val = *(const u16x8*)(Tt + o*128 + ((c ^ (o & 7)) << 4));
    *(u16x8*)((char*)hpz2 + ((size_t)(bh1*256 + (jbase >> 3) + c)*64 + o)*16) = val;
  }
  if (tid < 64){
    srcv[(size_t)bh1*NSEQ + jbase + tid] = (psumS[tid*2] + psumS[tid*2 + 1]) * LOG2E;
    dstv[(size_t)bh1*NSEQ + jbase + tid] = (psumD[tid*2] + psumD[tid*2 + 1]) * LOG2E;
  }
}

// ---------------------------------------------------------------------------
// Kernel B v2-PROBE: byte-identical round-3 main loop, executed TWICE inside
// one dispatch (idempotent; accs re-zeroed, pointers reset; memory clobber
// defeats cross-rep CSE). Purpose: push the dispatch to ~2A = 75-85 us so it
// finally lands in the rocprof top-5 with full counters. dur - 115.7 = A.
// ---------------------------------------------------------------------------
__global__ __launch_bounds__(512, 4) void k_attn(
    const unsigned short* __restrict__ hpz2, const float* __restrict__ srcv,
    const float* __restrict__ dstv, const float* __restrict__ bias,
    float* __restrict__ out)
{
  __shared__ __align__(16) char smem[33792];   // ob@0 (32 KB), Lbuf@32768
  float* Lbuf = (float*)(smem + 32768);        // [8][32]

  const int tid = threadIdx.x;
  const int bid = blockIdx.x;
  const int bh  = (bid & 7) | (((bid >> 3) & 1) << 3);
  const int i0  = (bid >> 4) << 6;
  const int wave = tid >> 6, lane = tid & 63;
  const int wm = wave & 1, jw = wave >> 1;
  const int l32 = lane & 31, h32 = lane >> 5;

  const float s2 = srcv[(size_t)bh*NSEQ + i0 + wm*32 + l32];
  const float u_ = s2;
  const float v_ = 0.2f*s2;

  const u16x8* gp = (const u16x8*)((const char*)hpz2 + (size_t)bh*256*64*16);

  f32x16 accO0, accO1;
  float lpart;

  for (int rep = 0; rep < 2; ++rep){
    asm volatile("" ::: "memory");     // force re-execution of loads each rep
    const u16x8* tp = gp + ((jw*4 + h32)*64 + l32);
    const float* dS = dstv + (size_t)bh*NSEQ + (jw*4 + h32)*8;
    accO0 = (f32x16){0,0,0,0,0,0,0,0,0,0,0,0,0,0,0,0};
    accO1 = (f32x16){0,0,0,0,0,0,0,0,0,0,0,0,0,0,0,0};
    lpart = 0.f;

    u16x8 c0 = tp[0], c1 = tp[32], c2 = tp[128], c3 = tp[160];

    for (int w = 0; w < 16; ++w){
      u16x8 n0, n1, n2, n3;
      if (w < 15){
        const u16x8* np = tp + 1024;
        n0 = np[0]; n1 = np[32]; n2 = np[128]; n3 = np[160];
      }
      float4 d0 = *(const float4*)(dS);
      float4 d1 = *(const float4*)(dS + 4);
      float4 d2 = *(const float4*)(dS + 16);
      float4 d3 = *(const float4*)(dS + 20);
      {
        float e0 = fexp2(fmaxf(u_ + d0.x, fmaf(0.2f, d0.x, v_)));
        float e1 = fexp2(fmaxf(u_ + d0.y, fmaf(0.2f, d0.y, v_)));
        float e2 = fexp2(fmaxf(u_ + d0.z, fmaf(0.2f, d0.z, v_)));
        float e3 = fexp2(fmaxf(u_ + d0.w, fmaf(0.2f, d0.w, v_)));
        float e4 = fexp2(fmaxf(u_ + d1.x, fmaf(0.2f, d1.x, v_)));
        float e5 = fexp2(fmaxf(u_ + d1.y, fmaf(0.2f, d1.y, v_)));
        float e6 = fexp2(fmaxf(u_ + d1.z, fmaf(0.2f, d1.z, v_)));
        float e7 = fexp2(fmaxf(u_ + d1.w, fmaf(0.2f, d1.w, v_)));
        lpart += ((e0+e1)+(e2+e3)) + ((e4+e5)+(e6+e7));
        u32x4 pk;
        pk[0] = pkbf(e0, e1); pk[1] = pkbf(e2, e3);
        pk[2] = pkbf(e4, e5); pk[3] = pkbf(e6, e7);
        const bf16x8 pA = __builtin_bit_cast(bf16x8, pk);
        accO0 = __builtin_amdgcn_mfma_f32_32x32x16_bf16(pA, c0, accO0, 0, 0, 0);
        accO1 = __builtin_amdgcn_mfma_f32_32x32x16_bf16(pA, c1, accO1, 0, 0, 0);
      }
      {
        float e0 = fexp2(fmaxf(u_ + d2.x, fmaf(0.2f, d2.x, v_)));
        float e1 = fexp2(fmaxf(u_ + d2.y, fmaf(0.2f, d2.y, v_)));
        float e2 = fexp2(fmaxf(u_ + d2.z, fmaf(0.2f, d2.z, v_)));
        float e3 = fexp2(fmaxf(u_ + d2.w, fmaf(0.2f, d2.w, v_)));
        float e4 = fexp2(fmaxf(u_ + d3.x, fmaf(0.2f, d3.x, v_)));
        float e5 = fexp2(fmaxf(u_ + d3.y, fmaf(0.2f, d3.y, v_)));
        float e6 = fexp2(fmaxf(u_ + d3.z, fmaf(0.2f, d3.z, v_)));
        float e7 = fexp2(fmaxf(u_ + d3.w, fmaf(0.2f, d3.w, v_)));
        lpart += ((e0+e1)+(e2+e3)) + ((e4+e5)+(e6+e7));
        u32x4 pk;
        pk[0] = pkbf(e0, e1); pk[1] = pkbf(e2, e3);
        pk[2] = pkbf(e4, e5); pk[3] = pkbf(e6, e7);
        const bf16x8 pA = __builtin_bit_cast(bf16x8, pk);
        accO0 = __builtin_amdgcn_mfma_f32_32x32x16_bf16(pA, c2, accO0, 0, 0, 0);
        accO1 = __builtin_amdgcn_mfma_f32_32x32x16_bf16(pA, c3, accO1, 0, 0, 0);
      }
      tp += 1024; dS += 128;
      c0 = n0; c1 = n1; c2 = n2; c3 = n3;
    }
  }

  lpart += __shfl_xor(lpart, 32);
  if (lane < 32) Lbuf[(wm*4 + jw)*32 + l32] = lpart;

  const float4 bia = *(const float4*)(bias + (tid & 15)*4);
  #pragma unroll
  for (int ph = 0; ph < 2; ++ph){
    __syncthreads();
    if (wm == ph){
      float* ob = (float*)smem;
      #pragma unroll
      for (int reg = 0; reg < 16; ++reg){
        const int m = (reg & 3) + 8*(reg >> 2) + 4*h32;
        ob[(jw*32 + m)*64 +      l32] = accO0[reg];
        ob[(jw*32 + m)*64 + 32 + l32] = accO1[reg];
      }
    }
    __syncthreads();
    {
      const int i = tid >> 4, o4 = (tid & 15)*4;
      const float* ob = (const float*)smem;
      float4 v0 = *(const float4*)(ob + (0*32 + i)*64 + o4);
      float4 v1 = *(const float4*)(ob + (1*32 + i)*64 + o4);
      float4 v2 = *(const float4*)(ob + (2*32 + i)*64 + o4);
      float4 v3 = *(const float4*)(ob + (3*32 + i)*64 + o4);
      const float l = Lbuf[(ph*4+0)*32 + i] + Lbuf[(ph*4+1)*32 + i]
                    + Lbuf[(ph*4+2)*32 + i] + Lbuf[(ph*4+3)*32 + i];
      const float r = 1.f / l;
      float4 res;
      res.x = (v0.x + v1.x + v2.x + v3.x)*r + bia.x;
      res.y = (v0.y + v1.y + v2.y + v3.y)*r + bia.y;
      res.z = (v0.z + v1.z + v2.z + v3.z)*r + bia.z;
      res.w = (v0.w + v1.w + v2.w + v3.w)*r + bia.w;
      *(float4*)(out + ((size_t)bh*NSEQ + i0 + ph*32 + i)*64 + o4) = res;
    }
  }
}

// ---------------------------------------------------------------------------
extern "C" void kernel_launch(void* const* d_in, const int* in_sizes, int n_in,
                              void* d_out, int out_size, void* d_ws, size_t ws_size,
                              hipStream_t stream)
{
  const float* h     = (const float*)d_in[0];
  const float* w     = (const float*)d_in[1];
  const float* a_src = (const float*)d_in[2];
  const float* a_dst = (const float*)d_in[3];
  const float* bias  = (const float*)d_in[4];
  float* out = (float*)d_out;

  char* ws = (char*)d_ws;
  unsigned short* hpz2 = (unsigned short*)ws;                 // 4 MB bf16 chunk-linear
  float* srcv = (float*)(ws + (4u<<20));                      // 128 KB (log2-scaled)
  float* dstv = (float*)(ws + (4u<<20) + (128u<<10));         // 128 KB (log2-scaled)

  k_hprime<<<512, 512, 0, stream>>>(h, w, a_src, a_dst, hpz2, srcv, dstv);
  k_attn<<<512, 512, 0, stream>>>(hpz2, srcv, dstv, bias, out);
}

// Round 10
// 119.983 us; speedup vs baseline: 3.3754x; 1.1205x over previous
//
#include <hip/hip_runtime.h>
#include <hip/hip_bf16.h>

#define NHEAD 4
#define FIN   768
#define FOUT  64
#define BSZ   4
#define NSEQ  2048
#define BH    (BSZ*NHEAD)
#define LOG2E 1.44269504088896f

typedef __attribute__((ext_vector_type(8)))  short bf16x8;   // MFMA A/B frag
typedef __attribute__((ext_vector_type(16))) float f32x16;   // MFMA 32x32 C/D
typedef __attribute__((ext_vector_type(8)))  unsigned short u16x8;
typedef __attribute__((ext_vector_type(4)))  unsigned short u16x4;
typedef __attribute__((ext_vector_type(4)))  unsigned u32x4;

__device__ __forceinline__ unsigned short f2bf(float f){
  unsigned b = __float_as_uint(f);
  return (unsigned short)((b + 0x7fffu + ((b >> 16) & 1u)) >> 16);
}
__device__ __forceinline__ float fexp2(float x){
#if __has_builtin(__builtin_amdgcn_exp2f)
  return __builtin_amdgcn_exp2f(x);
#else
  return exp2f(x);
#endif
}
__device__ __forceinline__ unsigned pkbf(float lo, float hi){
#if __has_builtin(__builtin_amdgcn_cvt_pk_bf16_f32)
  typedef __attribute__((ext_vector_type(2))) __bf16 bf2;
  union { bf2 v; unsigned u; } cv;
  cv.v = __builtin_amdgcn_cvt_pk_bf16_f32(lo, hi);
  return cv.u;
#else
  return (unsigned)f2bf(lo) | ((unsigned)f2bf(hi) << 16);
#endif
}
// fast tanh via exp2: tanh(v) = 1 - 2/(exp2(2*log2e*v)+1). |err| ~1e-7.
__device__ __forceinline__ float fast_tanh(float v){
  const float e = fexp2(v * (2.0f*LOG2E));
#if __has_builtin(__builtin_amdgcn_rcpf)
  return 1.0f - 2.0f*__builtin_amdgcn_rcpf(e + 1.0f);
#else
  return 1.0f - 2.0f/(e + 1.0f);
#endif
}

// ---------------------------------------------------------------------------
// Kernel A v7: identical proven GEMM (round-5 v5) but the epilogue now emits
// the EXP2-FACTORED score vectors instead of raw log2 scores:
//   cv[i]  = 2^{-0.8 S_i}   Ehv[j] = 2^{D_j}   Elv[j] = 2^{0.2 D_j}
// so k_attn computes q_ij = max(Ehv[j], cv[i]*Elv[j]) with ZERO exp2 in the
// O(N^2) loop (softmax row-scale 2^{S_i} cancels in accO/l).
// ---------------------------------------------------------------------------
__global__ __launch_bounds__(512, 4) void k_hprime(
    const float* __restrict__ h, const float* __restrict__ w,
    const float* __restrict__ a_src, const float* __restrict__ a_dst,
    unsigned short* __restrict__ hpz2, float* __restrict__ cv,
    float* __restrict__ Ehv, float* __restrict__ Elv)
{
  __shared__ __align__(16) char smem[65536];
  float* psumS = (float*)(smem + 16384);
  float* psumD = (float*)(smem + 16896);
  char*  Tt    = smem + 32768;

  const int tid  = threadIdx.x;
  const int bid  = blockIdx.x;
  const int bh1  = (bid & 7) | (((bid >> 3) & 1) << 3);
  const int head = bh1 & 3;
  const int jbase = (bid >> 4) << 6;
  const int i0a   = (bh1 >> 2)*NSEQ + jbase;
  const int wave = tid >> 6, lane = tid & 63;
  const int wm = wave & 1, wn = (wave >> 1) & 1, kw = wave >> 2;
  const int l32 = lane & 31, h32 = lane >> 5;

  f32x16 acc = {0,0,0,0,0,0,0,0,0,0,0,0,0,0,0,0};

  const int sr = tid >> 3, sc = tid & 7;
  const float* hA = h + (size_t)(i0a + sr)*FIN + sc*8;
  const int aslot = (sc ^ (sr & 7)) << 4;

  const int ob = tid & 63, cc = tid >> 6;
  const float* wsrc = w + (size_t)head*FIN*FOUT + ob;
  const int bslot0 = ((cc & 7) ^ (ob & 7)) << 4;

  float4 ra0 = *(const float4*)(hA);
  float4 ra1 = *(const float4*)(hA + 4);
  float4 ra2 = *(const float4*)(hA + 64);
  float4 ra3 = *(const float4*)(hA + 68);
  float rb[16];
  #pragma unroll
  for (int j = 0; j < 8; ++j){
    rb[j]     = wsrc[(size_t)(cc*8 + j)*FOUT];
    rb[8 + j] = wsrc[(size_t)(64 + cc*8 + j)*FOUT];
  }

  for (int it = 0; it < 6; ++it){
    char* Ab = smem +         (it & 1)*16384;
    char* Bb = smem + 32768 + (it & 1)*16384;
    u32x4 pk0, pk1;
    pk0[0] = pkbf(ra0.x, ra0.y); pk0[1] = pkbf(ra0.z, ra0.w);
    pk0[2] = pkbf(ra1.x, ra1.y); pk0[3] = pkbf(ra1.z, ra1.w);
    pk1[0] = pkbf(ra2.x, ra2.y); pk1[1] = pkbf(ra2.z, ra2.w);
    pk1[2] = pkbf(ra3.x, ra3.y); pk1[3] = pkbf(ra3.z, ra3.w);
    u32x4 qb0, qb1;
    qb0[0] = pkbf(rb[0],  rb[1]);  qb0[1] = pkbf(rb[2],  rb[3]);
    qb0[2] = pkbf(rb[4],  rb[5]);  qb0[3] = pkbf(rb[6],  rb[7]);
    qb1[0] = pkbf(rb[8],  rb[9]);  qb1[1] = pkbf(rb[10], rb[11]);
    qb1[2] = pkbf(rb[12], rb[13]); qb1[3] = pkbf(rb[14], rb[15]);
    if (it < 5){
      const float* an = hA + (it+1)*128;
      ra0 = *(const float4*)(an);      ra1 = *(const float4*)(an + 4);
      ra2 = *(const float4*)(an + 64); ra3 = *(const float4*)(an + 68);
      const float* wn_ = wsrc + (size_t)(it+1)*128*FOUT;
      #pragma unroll
      for (int j = 0; j < 8; ++j){
        rb[j]     = wn_[(size_t)(cc*8 + j)*FOUT];
        rb[8 + j] = wn_[(size_t)(64 + cc*8 + j)*FOUT];
      }
    }
    *(u32x4*)(Ab + sr*256 + aslot)        = pk0;
    *(u32x4*)(Ab + sr*256 + 128 + aslot)  = pk1;
    *(u32x4*)(Bb + ob*256 +       bslot0) = qb0;
    *(u32x4*)(Bb + ob*256 + 128 + bslot0) = qb1;
    asm volatile("s_waitcnt lgkmcnt(0)" ::: "memory");
    __builtin_amdgcn_s_barrier();
    __builtin_amdgcn_sched_barrier(0);
    #pragma unroll
    for (int s = 0; s < 4; ++s){
      const int slot = (((s*2 + h32) ^ (l32 & 7)) << 4);
      bf16x8 av = *(const bf16x8*)(Ab + (wm*32 + l32)*256 + kw*128 + slot);
      bf16x8 bv = *(const bf16x8*)(Bb + (wn*32 + l32)*256 + kw*128 + slot);
      acc = __builtin_amdgcn_mfma_f32_32x32x16_bf16(av, bv, acc, 0, 0, 0);
    }
  }

  if (kw == 1) *(f32x16*)(smem + (size_t)((wave & 3)*64 + lane)*64) = acc;
  __syncthreads();
  if (kw == 0){
    acc += *(const f32x16*)(smem + (size_t)((wave & 3)*64 + lane)*64);
    const float as = a_src[head*64 + wn*32 + l32];
    const float ad = a_dst[head*64 + wn*32 + l32];
    #pragma unroll
    for (int rb2 = 0; rb2 < 4; ++rb2){
      const int jb = wm*32 + rb2*8 + h32*4;
      u16x4 c4;
      #pragma unroll
      for (int q = 0; q < 4; ++q){
        const float v = acc[rb2*4 + q];
        c4[q] = f2bf(v);
        const float t = fast_tanh(v);
        float ps = t*as, pd = t*ad;
        ps += __shfl_xor(ps, 1);  ps += __shfl_xor(ps, 2);  ps += __shfl_xor(ps, 4);
        ps += __shfl_xor(ps, 8);  ps += __shfl_xor(ps, 16);
        pd += __shfl_xor(pd, 1);  pd += __shfl_xor(pd, 2);  pd += __shfl_xor(pd, 4);
        pd += __shfl_xor(pd, 8);  pd += __shfl_xor(pd, 16);
        if (l32 == 0){
          psumS[(jb + q)*2 + wn] = ps;
          psumD[(jb + q)*2 + wn] = pd;
        }
      }
      const int orow = wn*32 + l32;
      const int slot = ((jb >> 3) & 7) ^ (orow & 7);
      *(u16x4*)(Tt + orow*128 + slot*16 + (jb & 7)*2) = c4;
    }
  }
  __syncthreads();

  {
    const int o = tid & 63, c = tid >> 6;
    u16x8 val = *(const u16x8*)(Tt + o*128 + ((c ^ (o & 7)) << 4));
    *(u16x8*)((char*)hpz2 + ((size_t)(bh1*256 + (jbase >> 3) + c)*64 + o)*16) = val;
  }
  if (tid < 64){
    // log2-scaled scores; |S|,|D| <= ~28.1 -> all exp2 in fp32-safe range
    const float S = (psumS[tid*2] + psumS[tid*2 + 1]) * LOG2E;
    const float D = (psumD[tid*2] + psumD[tid*2 + 1]) * LOG2E;
    const size_t ix = (size_t)bh1*NSEQ + jbase + tid;
    cv [ix] = fexp2(-0.8f*S);     // 2^{-0.8 S_i}, in [2^-22.5, 2^22.5]
    Ehv[ix] = fexp2(D);           // 2^{D_j}
    Elv[ix] = fexp2(0.2f*D);      // 2^{0.2 D_j}
  }
}

// ---------------------------------------------------------------------------
// Kernel B v5: VALU strength reduction. Old per-element chain was
// add+fma+fmax+EXP2+add (~17 cyc with quarter-rate exp2, VALUBusy 71%
// measured R9). New: q = fmaxf(Eh_j, c_i*El_j) -- mul+max+add (~7 cyc),
// zero transcendentals in the O(N^2) loop. Identical math: row-scale 2^{S_i}
// cancels in accO/l (softmax scale invariance); max commutes with 2^x.
// Barrier-free direct-global structure from round 3 (best measured).
// ---------------------------------------------------------------------------
__global__ __launch_bounds__(512, 4) void k_attn(
    const unsigned short* __restrict__ hpz2, const float* __restrict__ cv,
    const float* __restrict__ Ehv, const float* __restrict__ Elv,
    const float* __restrict__ bias, float* __restrict__ out)
{
  __shared__ __align__(16) char smem[33792];   // ob@0 (32 KB), Lbuf@32768
  float* Lbuf = (float*)(smem + 32768);        // [8][32]

  const int tid = threadIdx.x;
  const int bid = blockIdx.x;
  const int bh  = (bid & 7) | (((bid >> 3) & 1) << 3);
  const int i0  = (bid >> 4) << 6;
  const int wave = tid >> 6, lane = tid & 63;
  const int wm = wave & 1, jw = wave >> 1;
  const int l32 = lane & 31, h32 = lane >> 5;

  const float c_ = cv[(size_t)bh*NSEQ + i0 + wm*32 + l32];   // 2^{-0.8 S_i}

  // B fragments: unit(w,Jl,half,l32) = w*1024 + Jl*64 + half*32 + l32
  const u16x8* gp = (const u16x8*)((const char*)hpz2 + (size_t)bh*256*64*16);
  const u16x8* tp = gp + ((jw*4 + h32)*64 + l32);
  const float* ehS = Ehv + (size_t)bh*NSEQ + (jw*4 + h32)*8;
  const float* elS = Elv + (size_t)bh*NSEQ + (jw*4 + h32)*8;

  f32x16 accO0 = {0,0,0,0,0,0,0,0,0,0,0,0,0,0,0,0};
  f32x16 accO1 = {0,0,0,0,0,0,0,0,0,0,0,0,0,0,0,0};
  float lpart = 0.f;

  u16x8 c0 = tp[0], c1 = tp[32], c2 = tp[128], c3 = tp[160];

  for (int w = 0; w < 16; ++w){
    u16x8 n0, n1, n2, n3;
    if (w < 15){
      const u16x8* np = tp + 1024;
      n0 = np[0]; n1 = np[32]; n2 = np[128]; n3 = np[160];
    }
    float4 eh0 = *(const float4*)(ehS);
    float4 eh1 = *(const float4*)(ehS + 4);
    float4 eh2 = *(const float4*)(ehS + 16);
    float4 eh3 = *(const float4*)(ehS + 20);
    float4 el0 = *(const float4*)(elS);
    float4 el1 = *(const float4*)(elS + 4);
    float4 el2 = *(const float4*)(elS + 16);
    float4 el3 = *(const float4*)(elS + 20);
    // stl0 (j rows jw*4 + h32)
    {
      float q0 = fmaxf(eh0.x, c_*el0.x);
      float q1 = fmaxf(eh0.y, c_*el0.y);
      float q2 = fmaxf(eh0.z, c_*el0.z);
      float q3 = fmaxf(eh0.w, c_*el0.w);
      float q4 = fmaxf(eh1.x, c_*el1.x);
      float q5 = fmaxf(eh1.y, c_*el1.y);
      float q6 = fmaxf(eh1.z, c_*el1.z);
      float q7 = fmaxf(eh1.w, c_*el1.w);
      lpart += ((q0+q1)+(q2+q3)) + ((q4+q5)+(q6+q7));
      u32x4 pk;
      pk[0] = pkbf(q0, q1); pk[1] = pkbf(q2, q3);
      pk[2] = pkbf(q4, q5); pk[3] = pkbf(q6, q7);
      const bf16x8 pA = __builtin_bit_cast(bf16x8, pk);
      accO0 = __builtin_amdgcn_mfma_f32_32x32x16_bf16(pA, c0, accO0, 0, 0, 0);
      accO1 = __builtin_amdgcn_mfma_f32_32x32x16_bf16(pA, c1, accO1, 0, 0, 0);
    }
    // stl1 (j rows jw*4 + 2 + h32)
    {
      float q0 = fmaxf(eh2.x, c_*el2.x);
      float q1 = fmaxf(eh2.y, c_*el2.y);
      float q2 = fmaxf(eh2.z, c_*el2.z);
      float q3 = fmaxf(eh2.w, c_*el2.w);
      float q4 = fmaxf(eh3.x, c_*el3.x);
      float q5 = fmaxf(eh3.y, c_*el3.y);
      float q6 = fmaxf(eh3.z, c_*el3.z);
      float q7 = fmaxf(eh3.w, c_*el3.w);
      lpart += ((q0+q1)+(q2+q3)) + ((q4+q5)+(q6+q7));
      u32x4 pk;
      pk[0] = pkbf(q0, q1); pk[1] = pkbf(q2, q3);
      pk[2] = pkbf(q4, q5); pk[3] = pkbf(q6, q7);
      const bf16x8 pA = __builtin_bit_cast(bf16x8, pk);
      accO0 = __builtin_amdgcn_mfma_f32_32x32x16_bf16(pA, c2, accO0, 0, 0, 0);
      accO1 = __builtin_amdgcn_mfma_f32_32x32x16_bf16(pA, c3, accO1, 0, 0, 0);
    }
    tp += 1024; ehS += 128; elS += 128;
    c0 = n0; c1 = n1; c2 = n2; c3 = n3;
  }

  lpart += __shfl_xor(lpart, 32);
  if (lane < 32) Lbuf[(wm*4 + jw)*32 + l32] = lpart;

  const float4 bia = *(const float4*)(bias + (tid & 15)*4);
  #pragma unroll
  for (int ph = 0; ph < 2; ++ph){
    __syncthreads();
    if (wm == ph){
      float* ob = (float*)smem;            // [jw][m 32][o 64] fp32 = 32 KB
      #pragma unroll
      for (int reg = 0; reg < 16; ++reg){
        const int m = (reg & 3) + 8*(reg >> 2) + 4*h32;
        ob[(jw*32 + m)*64 +      l32] = accO0[reg];
        ob[(jw*32 + m)*64 + 32 + l32] = accO1[reg];
      }
    }
    __syncthreads();
    {
      const int i = tid >> 4, o4 = (tid & 15)*4;
      const float* ob = (const float*)smem;
      float4 v0 = *(const float4*)(ob + (0*32 + i)*64 + o4);
      float4 v1 = *(const float4*)(ob + (1*32 + i)*64 + o4);
      float4 v2 = *(const float4*)(ob + (2*32 + i)*64 + o4);
      float4 v3 = *(const float4*)(ob + (3*32 + i)*64 + o4);
      const float l = Lbuf[(ph*4+0)*32 + i] + Lbuf[(ph*4+1)*32 + i]
                    + Lbuf[(ph*4+2)*32 + i] + Lbuf[(ph*4+3)*32 + i];
      const float r = 1.f / l;
      float4 res;
      res.x = (v0.x + v1.x + v2.x + v3.x)*r + bia.x;
      res.y = (v0.y + v1.y + v2.y + v3.y)*r + bia.y;
      res.z = (v0.z + v1.z + v2.z + v3.z)*r + bia.z;
      res.w = (v0.w + v1.w + v2.w + v3.w)*r + bia.w;
      *(float4*)(out + ((size_t)bh*NSEQ + i0 + ph*32 + i)*64 + o4) = res;
    }
  }
}

// ---------------------------------------------------------------------------
extern "C" void kernel_launch(void* const* d_in, const int* in_sizes, int n_in,
                              void* d_out, int out_size, void* d_ws, size_t ws_size,
                              hipStream_t stream)
{
  const float* h     = (const float*)d_in[0];
  const float* w     = (const float*)d_in[1];
  const float* a_src = (const float*)d_in[2];
  const float* a_dst = (const float*)d_in[3];
  const float* bias  = (const float*)d_in[4];
  float* out = (float*)d_out;

  char* ws = (char*)d_ws;
  unsigned short* hpz2 = (unsigned short*)ws;                 // 4 MB bf16 chunk-linear
  float* cv  = (float*)(ws + (4u<<20));                       // 128 KB  2^{-0.8 S}
  float* Ehv = (float*)(ws + (4u<<20) + (128u<<10));          // 128 KB  2^{D}
  float* Elv = (float*)(ws + (4u<<20) + (256u<<10));          // 128 KB  2^{0.2 D}

  k_hprime<<<512, 512, 0, stream>>>(h, w, a_src, a_dst, hpz2, cv, Ehv, Elv);
  k_attn<<<512, 512, 0, stream>>>(hpz2, cv, Ehv, Elv, bias, out);
}